// Round 4
// baseline (191.365 us; speedup 1.0000x reference)
//
#include <hip/hip_runtime.h>

// DCT_18769007084406: RGB->YCbCr (1x1 conv) -> 8x8 stride-8 block DCT
// (grouped conv) -> 32x repeated (t-min)/d normalization (closed form).
//
// R6: full load hoist. R5 (in-wave row-split, shfl_xor combine) fixed
// traffic (FETCH 74 MB, WRITE ideal) but sat at VALUBusy 24% / HBM 35%:
// VGPR=64 shows the compiler recycled load regs per row-iteration, so only
// ~6 loads/wave were in flight -> latency-bound on ~900cy HBM misses.
// Now all 24 float4 loads (4 rows x R,G,B x 2) are issued up-front into
// explicit arrays before any compute; __launch_bounds__(256,3) gives the
// allocator ~168 VGPRs to keep them live. 24 KB in flight per wave,
// ~12 waves/CU -> ~288 KB outstanding per CU: BW-saturating MLP.
// Everything else identical to R5.

#define HW 512
#define CHST (HW * HW)       // channel stride in x
#define NPAIR 6144           // 32 * 192 (b, out-channel) pairs
#define EPS 1e-6f

// basis[u][i] = c(u) * cos(pi*u*(i+0.5)/8); c(0)=sqrt(1/8), c(u>0)=0.5
static constexpr float BASIS[8][8] = {
  { 0.35355339059327373f, 0.35355339059327373f, 0.35355339059327373f, 0.35355339059327373f,
    0.35355339059327373f, 0.35355339059327373f, 0.35355339059327373f, 0.35355339059327373f },
  { 0.49039264020161522f, 0.41573480615127262f, 0.27778511650980114f, 0.09754516100806412f,
   -0.09754516100806412f,-0.27778511650980114f,-0.41573480615127262f,-0.49039264020161522f },
  { 0.46193976625564337f, 0.19134171618254492f,-0.19134171618254492f,-0.46193976625564337f,
   -0.46193976625564337f,-0.19134171618254492f, 0.19134171618254492f, 0.46193976625564337f },
  { 0.41573480615127262f,-0.09754516100806412f,-0.49039264020161522f,-0.27778511650980114f,
    0.27778511650980114f, 0.49039264020161522f, 0.09754516100806412f,-0.41573480615127262f },
  { 0.35355339059327373f,-0.35355339059327373f,-0.35355339059327373f, 0.35355339059327373f,
    0.35355339059327373f,-0.35355339059327373f,-0.35355339059327373f, 0.35355339059327373f },
  { 0.27778511650980114f,-0.49039264020161522f, 0.09754516100806412f, 0.41573480615127262f,
   -0.41573480615127262f,-0.09754516100806412f, 0.49039264020161522f,-0.27778511650980114f },
  { 0.19134171618254492f,-0.46193976625564337f, 0.46193976625564337f,-0.19134171618254492f,
   -0.19134171618254492f, 0.46193976625564337f,-0.46193976625564337f, 0.19134171618254492f },
  { 0.09754516100806412f,-0.27778511650980114f, 0.41573480615127262f,-0.49039264020161522f,
    0.49039264020161522f,-0.41573480615127262f, 0.27778511650980114f,-0.09754516100806412f }
};

// t_32 = a^32 * t0 - min * sum_{k=1..32} a^k, a = 1/(max-min+eps)
__global__ void precomp_norm(const float* __restrict__ max_,
                             const float* __restrict__ min_,
                             float* __restrict__ so) {
    int i = blockIdx.x * 256 + threadIdx.x;
    if (i >= NPAIR) return;
    float mn = min_[i], mx = max_[i];
    float d = mx - mn + EPS;
    float a = 1.0f / d;
    float a2 = a * a, a4 = a2 * a2, a8 = a4 * a4, a16 = a8 * a8, a32 = a16 * a16;
    float geo = a * (1.0f - a32) / (1.0f - a);   // sum_{k=1..32} a^k
    so[2 * i]     = a32;
    so[2 * i + 1] = -mn * geo;
}

template <bool USE_WS>
__global__ __launch_bounds__(256, 3)
void dct_kernel(const float* __restrict__ x,
                const float* __restrict__ ycbcr_w,
                const float* __restrict__ so,
                const float* __restrict__ max_,
                const float* __restrict__ min_,
                float* __restrict__ out) {
    // wave-task: band*6 + half*3 + c  (12288 total; the 3 channel-waves of
    // one half-band are consecutive -> same workgroup -> L1 share)
    const int wt   = blockIdx.x * 4 + (threadIdx.x >> 6);
    const int lane = threadIdx.x & 63;
    const int rh   = lane >> 5;            // row-half: rows rh*4 .. rh*4+3
    const int lx   = lane & 31;            // block-col within the half

    const int band = wt / 6;               // (b, by)
    const int rem  = wt - band * 6;
    const int half = (rem >= 3) ? 1 : 0;   // column half of the band
    const int c    = rem - half * 3;       // YCbCr channel
    const int by   = band & 63;
    const int b    = band >> 6;
    const int bx   = half * 32 + lx;       // this lane's 8x8 block column

    // channel weights (wave-uniform)
    const float wr = ycbcr_w[3 * c];
    const float wg = ycbcr_w[3 * c + 1];
    const float wb = ycbcr_w[3 * c + 2];

    // lane's 4 rows start here
    const float* base = x + (size_t)(b * 3) * CHST
                          + (size_t)(by * 8 + rh * 4) * HW + bx * 8;

    // ---- issue ALL loads first: 24 global_load_dwordx4, no compute between
    float4 Rv[4][2], Gv[4][2], Bv[4][2];
#pragma unroll
    for (int t = 0; t < 4; ++t) {
        const float* rp = base + t * HW;
        Rv[t][0] = *(const float4*)(rp);
        Rv[t][1] = *(const float4*)(rp + 4);
        Gv[t][0] = *(const float4*)(rp + CHST);
        Gv[t][1] = *(const float4*)(rp + CHST + 4);
        Bv[t][0] = *(const float4*)(rp + 2 * CHST);
        Bv[t][1] = *(const float4*)(rp + 2 * CHST + 4);
    }

    float acc[4][8];   // acc[u0][v] for u = rh*4 + u0
#pragma unroll
    for (int u0 = 0; u0 < 4; ++u0)
#pragma unroll
        for (int v = 0; v < 8; ++v) acc[u0][v] = 0.0f;

#pragma unroll
    for (int t = 0; t < 4; ++t) {
        float y[8];
        y[0] = fmaf(wr, Rv[t][0].x, fmaf(wg, Gv[t][0].x, wb * Bv[t][0].x));
        y[1] = fmaf(wr, Rv[t][0].y, fmaf(wg, Gv[t][0].y, wb * Bv[t][0].y));
        y[2] = fmaf(wr, Rv[t][0].z, fmaf(wg, Gv[t][0].z, wb * Bv[t][0].z));
        y[3] = fmaf(wr, Rv[t][0].w, fmaf(wg, Gv[t][0].w, wb * Bv[t][0].w));
        y[4] = fmaf(wr, Rv[t][1].x, fmaf(wg, Gv[t][1].x, wb * Bv[t][1].x));
        y[5] = fmaf(wr, Rv[t][1].y, fmaf(wg, Gv[t][1].y, wb * Bv[t][1].y));
        y[6] = fmaf(wr, Rv[t][1].z, fmaf(wg, Gv[t][1].z, wb * Bv[t][1].z));
        y[7] = fmaf(wr, Rv[t][1].w, fmaf(wg, Gv[t][1].w, wb * Bv[t][1].w));

        // row DCT: z[v] = sum_j basis[v][j] * y[j]
        float z[8];
#pragma unroll
        for (int v = 0; v < 8; ++v) {
            float zz = y[0] * BASIS[v][0];
#pragma unroll
            for (int j = 1; j < 8; ++j)
                zz = fmaf(y[j], BASIS[v][j], zz);
            z[v] = zz;
        }

        // partner row-half's z for the same block (lane ^ 32)
        float pz[8];
#pragma unroll
        for (int v = 0; v < 8; ++v)
            pz[v] = __shfl_xor(z[v], 32, 64);

        // column accumulate: own row gi = rh*4+t, partner row (1-rh)*4+t.
        // Compile-time indices, runtime rh -> v_cndmask between literals.
#pragma unroll
        for (int u0 = 0; u0 < 4; ++u0) {
            const float bo = rh ? BASIS[4 + u0][4 + t] : BASIS[u0][t];
            const float bp = rh ? BASIS[4 + u0][t]     : BASIS[u0][4 + t];
#pragma unroll
            for (int v = 0; v < 8; ++v)
                acc[u0][v] = fmaf(bo, z[v], fmaf(bp, pz[v], acc[u0][v]));
        }
    }

    const int obase = b * 192 + c * 64;    // first output channel index
    const int uh    = rh * 4;              // lane stores its u-half
    float* op = out + ((size_t)obase * 64 + by) * 64 + bx;
    const float2* sop = (const float2*)so + obase;   // (scale, offset) pairs

#pragma unroll
    for (int u0 = 0; u0 < 4; ++u0) {
#pragma unroll
        for (int v = 0; v < 8; ++v) {
            const int k = (uh + u0) * 8 + v;
            float s, o;
            if (USE_WS) {
                float2 p = sop[k];                 // L1-hit small table
                s = p.x;
                o = p.y;
            } else {
                float mn = min_[obase + k], mx = max_[obase + k];
                float d  = mx - mn + EPS;
                float a  = 1.0f / d;
                float a2 = a * a, a4 = a2 * a2, a8 = a4 * a4, a16 = a8 * a8, a32 = a16 * a16;
                s = a32;
                o = -mn * (a * (1.0f - a32) / (1.0f - a));
            }
            op[(size_t)k * 4096] = fmaf(s, acc[u0][v], o);
        }
    }
}

extern "C" void kernel_launch(void* const* d_in, const int* in_sizes, int n_in,
                              void* d_out, int out_size, void* d_ws, size_t ws_size,
                              hipStream_t stream) {
    const float* x    = (const float*)d_in[0];
    const float* max_ = (const float*)d_in[1];
    const float* min_ = (const float*)d_in[2];
    const float* yw   = (const float*)d_in[3];
    float* out = (float*)d_out;
    float* so  = (float*)d_ws;

    const bool use_ws = (ws_size >= (size_t)NPAIR * 2 * sizeof(float));
    // 12288 wave-tasks / 4 waves per 256-thread block = 3072 blocks
    if (use_ws) {
        precomp_norm<<<(NPAIR + 255) / 256, 256, 0, stream>>>(max_, min_, so);
        dct_kernel<true><<<3072, 256, 0, stream>>>(x, yw, so, max_, min_, out);
    } else {
        dct_kernel<false><<<3072, 256, 0, stream>>>(x, yw, nullptr, max_, min_, out);
    }
}

// Round 5
// 187.868 us; speedup vs baseline: 1.0186x; 1.0186x over previous
//
#include <hip/hip_runtime.h>

// DCT_18769007084406: RGB->YCbCr (1x1 conv) -> 8x8 stride-8 block DCT
// (grouped conv) -> 32x repeated (t-min)/d normalization (closed form).
//
// R7: R6's full load hoist FAILED silently -- VGPR_Count stayed 64, i.e.
// the MachineScheduler re-sank the 24 hoisted loads back next to their
// uses (source order is not binding), so MLP/wave never increased and
// dur stayed ~62us = 176MB @ 2.8TB/s (44% of achievable; latency-bound).
// Fix: __builtin_amdgcn_sched_barrier(0) between the load block and all
// compute. Nothing may cross the fence -> all 24 global_load_dwordx4
// issue first, allocator must keep them live (~96 load VGPRs).
// launch_bounds(256,2) (cap ~256 VGPR) removes spill risk; ~12 waves/CU
// x 24KB in flight/wave = ~290KB outstanding/CU >> BW*latency (~10KB).
// Mechanism check: VGPR must jump to ~150. If it's 64 again -> inline-asm
// loads next. Everything else identical to R5/R6.

#define HW 512
#define CHST (HW * HW)       // channel stride in x
#define NPAIR 6144           // 32 * 192 (b, out-channel) pairs
#define EPS 1e-6f

// basis[u][i] = c(u) * cos(pi*u*(i+0.5)/8); c(0)=sqrt(1/8), c(u>0)=0.5
static constexpr float BASIS[8][8] = {
  { 0.35355339059327373f, 0.35355339059327373f, 0.35355339059327373f, 0.35355339059327373f,
    0.35355339059327373f, 0.35355339059327373f, 0.35355339059327373f, 0.35355339059327373f },
  { 0.49039264020161522f, 0.41573480615127262f, 0.27778511650980114f, 0.09754516100806412f,
   -0.09754516100806412f,-0.27778511650980114f,-0.41573480615127262f,-0.49039264020161522f },
  { 0.46193976625564337f, 0.19134171618254492f,-0.19134171618254492f,-0.46193976625564337f,
   -0.46193976625564337f,-0.19134171618254492f, 0.19134171618254492f, 0.46193976625564337f },
  { 0.41573480615127262f,-0.09754516100806412f,-0.49039264020161522f,-0.27778511650980114f,
    0.27778511650980114f, 0.49039264020161522f, 0.09754516100806412f,-0.41573480615127262f },
  { 0.35355339059327373f,-0.35355339059327373f,-0.35355339059327373f, 0.35355339059327373f,
    0.35355339059327373f,-0.35355339059327373f,-0.35355339059327373f, 0.35355339059327373f },
  { 0.27778511650980114f,-0.49039264020161522f, 0.09754516100806412f, 0.41573480615127262f,
   -0.41573480615127262f,-0.09754516100806412f, 0.49039264020161522f,-0.27778511650980114f },
  { 0.19134171618254492f,-0.46193976625564337f, 0.46193976625564337f,-0.19134171618254492f,
   -0.19134171618254492f, 0.46193976625564337f,-0.46193976625564337f, 0.19134171618254492f },
  { 0.09754516100806412f,-0.27778511650980114f, 0.41573480615127262f,-0.49039264020161522f,
    0.49039264020161522f,-0.41573480615127262f, 0.27778511650980114f,-0.09754516100806412f }
};

// t_32 = a^32 * t0 - min * sum_{k=1..32} a^k, a = 1/(max-min+eps)
__global__ void precomp_norm(const float* __restrict__ max_,
                             const float* __restrict__ min_,
                             float* __restrict__ so) {
    int i = blockIdx.x * 256 + threadIdx.x;
    if (i >= NPAIR) return;
    float mn = min_[i], mx = max_[i];
    float d = mx - mn + EPS;
    float a = 1.0f / d;
    float a2 = a * a, a4 = a2 * a2, a8 = a4 * a4, a16 = a8 * a8, a32 = a16 * a16;
    float geo = a * (1.0f - a32) / (1.0f - a);   // sum_{k=1..32} a^k
    so[2 * i]     = a32;
    so[2 * i + 1] = -mn * geo;
}

template <bool USE_WS>
__global__ __launch_bounds__(256, 2)
void dct_kernel(const float* __restrict__ x,
                const float* __restrict__ ycbcr_w,
                const float* __restrict__ so,
                const float* __restrict__ max_,
                const float* __restrict__ min_,
                float* __restrict__ out) {
    // wave-task: band*6 + half*3 + c  (12288 total; the 3 channel-waves of
    // one half-band are consecutive -> same workgroup -> L1 share)
    const int wt   = blockIdx.x * 4 + (threadIdx.x >> 6);
    const int lane = threadIdx.x & 63;
    const int rh   = lane >> 5;            // row-half: rows rh*4 .. rh*4+3
    const int lx   = lane & 31;            // block-col within the half

    const int band = wt / 6;               // (b, by)
    const int rem  = wt - band * 6;
    const int half = (rem >= 3) ? 1 : 0;   // column half of the band
    const int c    = rem - half * 3;       // YCbCr channel
    const int by   = band & 63;
    const int b    = band >> 6;
    const int bx   = half * 32 + lx;       // this lane's 8x8 block column

    // channel weights (wave-uniform)
    const float wr = ycbcr_w[3 * c];
    const float wg = ycbcr_w[3 * c + 1];
    const float wb = ycbcr_w[3 * c + 2];

    // lane's 4 rows start here
    const float* base = x + (size_t)(b * 3) * CHST
                          + (size_t)(by * 8 + rh * 4) * HW + bx * 8;

    // ---- issue ALL loads first: 24 global_load_dwordx4 ----
    float4 Rv[4][2], Gv[4][2], Bv[4][2];
#pragma unroll
    for (int t = 0; t < 4; ++t) {
        const float* rp = base + t * HW;
        Rv[t][0] = *(const float4*)(rp);
        Rv[t][1] = *(const float4*)(rp + 4);
        Gv[t][0] = *(const float4*)(rp + CHST);
        Gv[t][1] = *(const float4*)(rp + CHST + 4);
        Bv[t][0] = *(const float4*)(rp + 2 * CHST);
        Bv[t][1] = *(const float4*)(rp + 2 * CHST + 4);
    }
    // Scheduling fence: nothing crosses. Loads cannot be re-sunk below;
    // the allocator must keep all 24 results live -> true MLP.
    __builtin_amdgcn_sched_barrier(0);

    float acc[4][8];   // acc[u0][v] for u = rh*4 + u0
#pragma unroll
    for (int u0 = 0; u0 < 4; ++u0)
#pragma unroll
        for (int v = 0; v < 8; ++v) acc[u0][v] = 0.0f;

#pragma unroll
    for (int t = 0; t < 4; ++t) {
        float y[8];
        y[0] = fmaf(wr, Rv[t][0].x, fmaf(wg, Gv[t][0].x, wb * Bv[t][0].x));
        y[1] = fmaf(wr, Rv[t][0].y, fmaf(wg, Gv[t][0].y, wb * Bv[t][0].y));
        y[2] = fmaf(wr, Rv[t][0].z, fmaf(wg, Gv[t][0].z, wb * Bv[t][0].z));
        y[3] = fmaf(wr, Rv[t][0].w, fmaf(wg, Gv[t][0].w, wb * Bv[t][0].w));
        y[4] = fmaf(wr, Rv[t][1].x, fmaf(wg, Gv[t][1].x, wb * Bv[t][1].x));
        y[5] = fmaf(wr, Rv[t][1].y, fmaf(wg, Gv[t][1].y, wb * Bv[t][1].y));
        y[6] = fmaf(wr, Rv[t][1].z, fmaf(wg, Gv[t][1].z, wb * Bv[t][1].z));
        y[7] = fmaf(wr, Rv[t][1].w, fmaf(wg, Gv[t][1].w, wb * Bv[t][1].w));

        // row DCT: z[v] = sum_j basis[v][j] * y[j]
        float z[8];
#pragma unroll
        for (int v = 0; v < 8; ++v) {
            float zz = y[0] * BASIS[v][0];
#pragma unroll
            for (int j = 1; j < 8; ++j)
                zz = fmaf(y[j], BASIS[v][j], zz);
            z[v] = zz;
        }

        // partner row-half's z for the same block (lane ^ 32)
        float pz[8];
#pragma unroll
        for (int v = 0; v < 8; ++v)
            pz[v] = __shfl_xor(z[v], 32, 64);

        // column accumulate: own row gi = rh*4+t, partner row (1-rh)*4+t.
        // Compile-time indices, runtime rh -> v_cndmask between literals.
#pragma unroll
        for (int u0 = 0; u0 < 4; ++u0) {
            const float bo = rh ? BASIS[4 + u0][4 + t] : BASIS[u0][t];
            const float bp = rh ? BASIS[4 + u0][t]     : BASIS[u0][4 + t];
#pragma unroll
            for (int v = 0; v < 8; ++v)
                acc[u0][v] = fmaf(bo, z[v], fmaf(bp, pz[v], acc[u0][v]));
        }
    }

    const int obase = b * 192 + c * 64;    // first output channel index
    const int uh    = rh * 4;              // lane stores its u-half
    float* op = out + ((size_t)obase * 64 + by) * 64 + bx;
    const float2* sop = (const float2*)so + obase;   // (scale, offset) pairs

#pragma unroll
    for (int u0 = 0; u0 < 4; ++u0) {
#pragma unroll
        for (int v = 0; v < 8; ++v) {
            const int k = (uh + u0) * 8 + v;
            float s, o;
            if (USE_WS) {
                float2 p = sop[k];                 // L1-hit small table
                s = p.x;
                o = p.y;
            } else {
                float mn = min_[obase + k], mx = max_[obase + k];
                float d  = mx - mn + EPS;
                float a  = 1.0f / d;
                float a2 = a * a, a4 = a2 * a2, a8 = a4 * a4, a16 = a8 * a8, a32 = a16 * a16;
                s = a32;
                o = -mn * (a * (1.0f - a32) / (1.0f - a));
            }
            op[(size_t)k * 4096] = fmaf(s, acc[u0][v], o);
        }
    }
}

extern "C" void kernel_launch(void* const* d_in, const int* in_sizes, int n_in,
                              void* d_out, int out_size, void* d_ws, size_t ws_size,
                              hipStream_t stream) {
    const float* x    = (const float*)d_in[0];
    const float* max_ = (const float*)d_in[1];
    const float* min_ = (const float*)d_in[2];
    const float* yw   = (const float*)d_in[3];
    float* out = (float*)d_out;
    float* so  = (float*)d_ws;

    const bool use_ws = (ws_size >= (size_t)NPAIR * 2 * sizeof(float));
    // 12288 wave-tasks / 4 waves per 256-thread block = 3072 blocks
    if (use_ws) {
        precomp_norm<<<(NPAIR + 255) / 256, 256, 0, stream>>>(max_, min_, so);
        dct_kernel<true><<<3072, 256, 0, stream>>>(x, yw, so, max_, min_, out);
    } else {
        dct_kernel<false><<<3072, 256, 0, stream>>>(x, yw, nullptr, max_, min_, out);
    }
}

// Round 6
// 186.937 us; speedup vs baseline: 1.0237x; 1.0050x over previous
//
#include <hip/hip_runtime.h>

// DCT_18769007084406: RGB->YCbCr (1x1 conv) -> 8x8 stride-8 block DCT
// (grouped conv) -> 32x repeated (t-min)/d normalization (closed form).
//
// R8: inline-asm load burst + counted vmcnt waits. R6 (source hoist) and
// R7 (sched_barrier fence) both failed the VGPR mechanism check (stuck at
// 60-64): hipcc re-sinks hoisted loads before the scheduler ever sees the
// fence, so only ~6 loads/wave stay in flight -> ~900cy HBM latency is
// exposed per row -> 60us vs the ~30us BW floor (VALUBusy 25%, HBM 36%).
// Now the 24 global_load_dwordx4 are ONE asm volatile block (cannot be
// split or re-sunk; "=&v" early-clobber forces 24 live float4 results =
// 96 VGPRs), and consumption is phased with hand-counted
// s_waitcnt vmcnt(18/12/6/0) -- wait only for the 6 loads of row t, keep
// the rest in flight (T4 counted-wait pattern). sched_barrier(0) after
// each wait stops consumes hoisting above it (rule #18: compiler doesn't
// track asm-internal vmcnt). Compiler vmem ops can only add queue entries
// around our block -> our waits only get stronger, never weaker (safe).
// Everything else (R5 task split, shfl_xor row combine, epilogue) same.

#define HW 512
#define CHST (HW * HW)       // channel stride in x
#define NPAIR 6144           // 32 * 192 (b, out-channel) pairs
#define EPS 1e-6f

// basis[u][i] = c(u) * cos(pi*u*(i+0.5)/8); c(0)=sqrt(1/8), c(u>0)=0.5
static constexpr float BASIS[8][8] = {
  { 0.35355339059327373f, 0.35355339059327373f, 0.35355339059327373f, 0.35355339059327373f,
    0.35355339059327373f, 0.35355339059327373f, 0.35355339059327373f, 0.35355339059327373f },
  { 0.49039264020161522f, 0.41573480615127262f, 0.27778511650980114f, 0.09754516100806412f,
   -0.09754516100806412f,-0.27778511650980114f,-0.41573480615127262f,-0.49039264020161522f },
  { 0.46193976625564337f, 0.19134171618254492f,-0.19134171618254492f,-0.46193976625564337f,
   -0.46193976625564337f,-0.19134171618254492f, 0.19134171618254492f, 0.46193976625564337f },
  { 0.41573480615127262f,-0.09754516100806412f,-0.49039264020161522f,-0.27778511650980114f,
    0.27778511650980114f, 0.49039264020161522f, 0.09754516100806412f,-0.41573480615127262f },
  { 0.35355339059327373f,-0.35355339059327373f,-0.35355339059327373f, 0.35355339059327373f,
    0.35355339059327373f,-0.35355339059327373f,-0.35355339059327373f, 0.35355339059327373f },
  { 0.27778511650980114f,-0.49039264020161522f, 0.09754516100806412f, 0.41573480615127262f,
   -0.41573480615127262f,-0.09754516100806412f, 0.49039264020161522f,-0.27778511650980114f },
  { 0.19134171618254492f,-0.46193976625564337f, 0.46193976625564337f,-0.19134171618254492f,
   -0.19134171618254492f, 0.46193976625564337f,-0.46193976625564337f, 0.19134171618254492f },
  { 0.09754516100806412f,-0.27778511650980114f, 0.41573480615127262f,-0.49039264020161522f,
    0.49039264020161522f,-0.41573480615127262f, 0.27778511650980114f,-0.09754516100806412f }
};

// t_32 = a^32 * t0 - min * sum_{k=1..32} a^k, a = 1/(max-min+eps)
__global__ void precomp_norm(const float* __restrict__ max_,
                             const float* __restrict__ min_,
                             float* __restrict__ so) {
    int i = blockIdx.x * 256 + threadIdx.x;
    if (i >= NPAIR) return;
    float mn = min_[i], mx = max_[i];
    float d = mx - mn + EPS;
    float a = 1.0f / d;
    float a2 = a * a, a4 = a2 * a2, a8 = a4 * a4, a16 = a8 * a8, a32 = a16 * a16;
    float geo = a * (1.0f - a32) / (1.0f - a);   // sum_{k=1..32} a^k
    so[2 * i]     = a32;
    so[2 * i + 1] = -mn * geo;
}

// One input row t: YCbCr, row-DCT, cross-half combine, accumulate.
// T is compile-time so all BASIS indices fold to literals (rh -> cndmask).
template <int T>
__device__ __forceinline__ void row_compute(
    const int rh, const float wr, const float wg, const float wb,
    const float4& RA, const float4& RB, const float4& GA, const float4& GB,
    const float4& BA, const float4& BB, float acc[4][8])
{
    float y[8];
    y[0] = fmaf(wr, RA.x, fmaf(wg, GA.x, wb * BA.x));
    y[1] = fmaf(wr, RA.y, fmaf(wg, GA.y, wb * BA.y));
    y[2] = fmaf(wr, RA.z, fmaf(wg, GA.z, wb * BA.z));
    y[3] = fmaf(wr, RA.w, fmaf(wg, GA.w, wb * BA.w));
    y[4] = fmaf(wr, RB.x, fmaf(wg, GB.x, wb * BB.x));
    y[5] = fmaf(wr, RB.y, fmaf(wg, GB.y, wb * BB.y));
    y[6] = fmaf(wr, RB.z, fmaf(wg, GB.z, wb * BB.z));
    y[7] = fmaf(wr, RB.w, fmaf(wg, GB.w, wb * BB.w));

    // row DCT: z[v] = sum_j basis[v][j] * y[j]
    float z[8];
#pragma unroll
    for (int v = 0; v < 8; ++v) {
        float zz = y[0] * BASIS[v][0];
#pragma unroll
        for (int j = 1; j < 8; ++j)
            zz = fmaf(y[j], BASIS[v][j], zz);
        z[v] = zz;
    }

    // partner row-half's z for the same block (lane ^ 32)
    float pz[8];
#pragma unroll
    for (int v = 0; v < 8; ++v)
        pz[v] = __shfl_xor(z[v], 32, 64);

    // own row gi = rh*4+T, partner row (1-rh)*4+T
#pragma unroll
    for (int u0 = 0; u0 < 4; ++u0) {
        const float bo = rh ? BASIS[4 + u0][4 + T] : BASIS[u0][T];
        const float bp = rh ? BASIS[4 + u0][T]     : BASIS[u0][4 + T];
#pragma unroll
        for (int v = 0; v < 8; ++v)
            acc[u0][v] = fmaf(bo, z[v], fmaf(bp, pz[v], acc[u0][v]));
    }
}

template <bool USE_WS>
__global__ __launch_bounds__(256, 2)
void dct_kernel(const float* __restrict__ x,
                const float* __restrict__ ycbcr_w,
                const float* __restrict__ so,
                const float* __restrict__ max_,
                const float* __restrict__ min_,
                float* __restrict__ out) {
    // wave-task: band*6 + half*3 + c  (12288 total)
    const int wt   = blockIdx.x * 4 + (threadIdx.x >> 6);
    const int lane = threadIdx.x & 63;
    const int rh   = lane >> 5;            // row-half: rows rh*4 .. rh*4+3
    const int lx   = lane & 31;            // block-col within the half

    const int band = wt / 6;               // (b, by)
    const int rem  = wt - band * 6;
    const int half = (rem >= 3) ? 1 : 0;   // column half of the band
    const int c    = rem - half * 3;       // YCbCr channel
    const int by   = band & 63;
    const int b    = band >> 6;
    const int bx   = half * 32 + lx;       // this lane's 8x8 block column

    // channel weights (wave-uniform)
    const float wr = ycbcr_w[3 * c];
    const float wg = ycbcr_w[3 * c + 1];
    const float wb = ycbcr_w[3 * c + 2];

    // lane's 4 rows start here
    const float* base = x + (size_t)(b * 3) * CHST
                          + (size_t)(by * 8 + rh * 4) * HW + bx * 8;

    // 6 address pairs: rows t0/t1 via p*, rows t2/t3 via p*2 (+4096 B).
    // Per-row offsets within 13-bit signed imm: 0,16,2048,2064.
    const float* pr  = base;
    const float* pg  = base + CHST;
    const float* pb  = base + 2 * CHST;
    const float* pr2 = pr + 1024;
    const float* pg2 = pg + 1024;
    const float* pb2 = pb + 1024;

    float4 R0a, R0b, G0a, G0b, B0a, B0b;
    float4 R1a, R1b, G1a, G1b, B1a, B1b;
    float4 R2a, R2b, G2a, G2b, B2a, B2b;
    float4 R3a, R3b, G3a, G3b, B3a, B3b;

    // One indivisible burst of 24 loads, issued in row order t0..t3 so
    // vmcnt counts map to rows. "=&v" (early-clobber) keeps every dest
    // disjoint from the address regs (loads return asynchronously).
    asm volatile(
        "global_load_dwordx4 %[r0a], %[pr], off\n\t"
        "global_load_dwordx4 %[r0b], %[pr], off offset:16\n\t"
        "global_load_dwordx4 %[g0a], %[pg], off\n\t"
        "global_load_dwordx4 %[g0b], %[pg], off offset:16\n\t"
        "global_load_dwordx4 %[b0a], %[pb], off\n\t"
        "global_load_dwordx4 %[b0b], %[pb], off offset:16\n\t"
        "global_load_dwordx4 %[r1a], %[pr], off offset:2048\n\t"
        "global_load_dwordx4 %[r1b], %[pr], off offset:2064\n\t"
        "global_load_dwordx4 %[g1a], %[pg], off offset:2048\n\t"
        "global_load_dwordx4 %[g1b], %[pg], off offset:2064\n\t"
        "global_load_dwordx4 %[b1a], %[pb], off offset:2048\n\t"
        "global_load_dwordx4 %[b1b], %[pb], off offset:2064\n\t"
        "global_load_dwordx4 %[r2a], %[pr2], off\n\t"
        "global_load_dwordx4 %[r2b], %[pr2], off offset:16\n\t"
        "global_load_dwordx4 %[g2a], %[pg2], off\n\t"
        "global_load_dwordx4 %[g2b], %[pg2], off offset:16\n\t"
        "global_load_dwordx4 %[b2a], %[pb2], off\n\t"
        "global_load_dwordx4 %[b2b], %[pb2], off offset:16\n\t"
        "global_load_dwordx4 %[r3a], %[pr2], off offset:2048\n\t"
        "global_load_dwordx4 %[r3b], %[pr2], off offset:2064\n\t"
        "global_load_dwordx4 %[g3a], %[pg2], off offset:2048\n\t"
        "global_load_dwordx4 %[g3b], %[pg2], off offset:2064\n\t"
        "global_load_dwordx4 %[b3a], %[pb2], off offset:2048\n\t"
        "global_load_dwordx4 %[b3b], %[pb2], off offset:2064"
        : [r0a]"=&v"(R0a), [r0b]"=&v"(R0b), [g0a]"=&v"(G0a), [g0b]"=&v"(G0b),
          [b0a]"=&v"(B0a), [b0b]"=&v"(B0b),
          [r1a]"=&v"(R1a), [r1b]"=&v"(R1b), [g1a]"=&v"(G1a), [g1b]"=&v"(G1b),
          [b1a]"=&v"(B1a), [b1b]"=&v"(B1b),
          [r2a]"=&v"(R2a), [r2b]"=&v"(R2b), [g2a]"=&v"(G2a), [g2b]"=&v"(G2b),
          [b2a]"=&v"(B2a), [b2b]"=&v"(B2b),
          [r3a]"=&v"(R3a), [r3b]"=&v"(R3b), [g3a]"=&v"(G3a), [g3b]"=&v"(G3b),
          [b3a]"=&v"(B3a), [b3b]"=&v"(B3b)
        : [pr]"v"(pr), [pg]"v"(pg), [pb]"v"(pb),
          [pr2]"v"(pr2), [pg2]"v"(pg2), [pb2]"v"(pb2)
        : "memory");
    __builtin_amdgcn_sched_barrier(0);

    float acc[4][8];   // acc[u0][v] for u = rh*4 + u0
#pragma unroll
    for (int u0 = 0; u0 < 4; ++u0)
#pragma unroll
        for (int v = 0; v < 8; ++v) acc[u0][v] = 0.0f;

    // Phase waits: row t needs the 6*(t+1) oldest loads -> vmcnt(18/12/6/0).
    // sched_barrier(0) after each wait stops consumes hoisting above it
    // (compiler doesn't track asm-internal vmcnt); walls around compute
    // keep the phase structure intact.
    asm volatile("s_waitcnt vmcnt(18)" ::: "memory");
    __builtin_amdgcn_sched_barrier(0);
    row_compute<0>(rh, wr, wg, wb, R0a, R0b, G0a, G0b, B0a, B0b, acc);
    __builtin_amdgcn_sched_barrier(0);

    asm volatile("s_waitcnt vmcnt(12)" ::: "memory");
    __builtin_amdgcn_sched_barrier(0);
    row_compute<1>(rh, wr, wg, wb, R1a, R1b, G1a, G1b, B1a, B1b, acc);
    __builtin_amdgcn_sched_barrier(0);

    asm volatile("s_waitcnt vmcnt(6)" ::: "memory");
    __builtin_amdgcn_sched_barrier(0);
    row_compute<2>(rh, wr, wg, wb, R2a, R2b, G2a, G2b, B2a, B2b, acc);
    __builtin_amdgcn_sched_barrier(0);

    asm volatile("s_waitcnt vmcnt(0)" ::: "memory");
    __builtin_amdgcn_sched_barrier(0);
    row_compute<3>(rh, wr, wg, wb, R3a, R3b, G3a, G3b, B3a, B3b, acc);

    const int obase = b * 192 + c * 64;    // first output channel index
    const int uh    = rh * 4;              // lane stores its u-half
    float* op = out + ((size_t)obase * 64 + by) * 64 + bx;
    const float2* sop = (const float2*)so + obase;   // (scale, offset) pairs

#pragma unroll
    for (int u0 = 0; u0 < 4; ++u0) {
#pragma unroll
        for (int v = 0; v < 8; ++v) {
            const int k = (uh + u0) * 8 + v;
            float s, o;
            if (USE_WS) {
                float2 p = sop[k];                 // wave-uniform table
                s = p.x;
                o = p.y;
            } else {
                float mn = min_[obase + k], mx = max_[obase + k];
                float d  = mx - mn + EPS;
                float a  = 1.0f / d;
                float a2 = a * a, a4 = a2 * a2, a8 = a4 * a4, a16 = a8 * a8, a32 = a16 * a16;
                s = a32;
                o = -mn * (a * (1.0f - a32) / (1.0f - a));
            }
            op[(size_t)k * 4096] = fmaf(s, acc[u0][v], o);
        }
    }
}

extern "C" void kernel_launch(void* const* d_in, const int* in_sizes, int n_in,
                              void* d_out, int out_size, void* d_ws, size_t ws_size,
                              hipStream_t stream) {
    const float* x    = (const float*)d_in[0];
    const float* max_ = (const float*)d_in[1];
    const float* min_ = (const float*)d_in[2];
    const float* yw   = (const float*)d_in[3];
    float* out = (float*)d_out;
    float* so  = (float*)d_ws;

    const bool use_ws = (ws_size >= (size_t)NPAIR * 2 * sizeof(float));
    // 12288 wave-tasks / 4 waves per 256-thread block = 3072 blocks
    if (use_ws) {
        precomp_norm<<<(NPAIR + 255) / 256, 256, 0, stream>>>(max_, min_, so);
        dct_kernel<true><<<3072, 256, 0, stream>>>(x, yw, so, max_, min_, out);
    } else {
        dct_kernel<false><<<3072, 256, 0, stream>>>(x, yw, nullptr, max_, min_, out);
    }
}